// Round 16
// baseline (187.834 us; speedup 1.0000x reference)
//
#include <hip/hip_runtime.h>
#include <hip/hip_bf16.h>
#include <cstdint>
#include <cstddef>

// ---- types ----
typedef __attribute__((ext_vector_type(8))) short short8;       // 8 bf16 (4 VGPR) MFMA frag
typedef __attribute__((ext_vector_type(4))) float floatx4;      // MFMA accumulator
typedef __attribute__((ext_vector_type(2))) unsigned int uintx2;     // 8B vector st
typedef __attribute__((ext_vector_type(4))) unsigned int uintx4;     // 16B vector st

#define MFMA16(a, b, c) __builtin_amdgcn_mfma_f32_16x16x32_bf16((a), (b), (c), 0, 0, 0)
#define LOG2E 1.44269504088896340736f
#define EXP2(x) __builtin_amdgcn_exp2f(x)

__device__ __forceinline__ unsigned short f2bf(float f) {
  unsigned int u = __builtin_bit_cast(unsigned int, f);
  u += 0x7fffu + ((u >> 16) & 1u);          // RNE
  return (unsigned short)(u >> 16);
}

// packed bf16 pair via v_cvt_pk_bf16_f32 (RNE); memcpy avoids bit_cast restriction
__device__ __forceinline__ unsigned int pk2(float a, float b) {
  float2 f; f.x = a; f.y = b;
  __hip_bfloat162 h = __float22bfloat162_rn(f);
  unsigned int u;
  __builtin_memcpy(&u, &h, 4);
  return u;
}

typedef __attribute__((address_space(1))) void gvoid_t;
typedef __attribute__((address_space(3))) void svoid_t;
__device__ __forceinline__ void gload_lds16(const void* g, void* l) {
  // LDS dest = wave-uniform base + lane*16; global side is per-lane addresses.
  __builtin_amdgcn_global_load_lds((gvoid_t*)(uintptr_t)g, (svoid_t*)(uintptr_t)l, 16, 0, 0);
}

// ---------------- convert x: fp32 -> bf16 ----------------
__global__ void convert_x(const float* __restrict__ x, unsigned short* __restrict__ xb) {
  int i = (blockIdx.x * 256 + threadIdx.x) * 4;
  floatx4 v = *(const floatx4*)(x + i);
  uintx2 o;
  o[0] = pk2(v[0], v[1]);
  o[1] = pk2(v[2], v[3]);
  *(uintx2*)(xb + i) = o;
}

// ---------------- transpose weights -> bf16 N x K ----------------
__global__ void transpose_w(const float* __restrict__ Wq, const float* __restrict__ Wk,
                            const float* __restrict__ Wv, const float* __restrict__ Wo,
                            unsigned short* __restrict__ Wqkvt, unsigned short* __restrict__ Wot) {
  __shared__ float tile[32][33];
  int z = blockIdx.z;
  const float* W = (z == 0) ? Wq : (z == 1) ? Wk : (z == 2) ? Wv : Wo;
  unsigned short* out = (z == 3) ? Wot : (Wqkvt + (size_t)z * 1024 * 1024);
  int n0 = blockIdx.x * 32, k0 = blockIdx.y * 32;
  int tx = threadIdx.x, ty = threadIdx.y;            // block (32,8)
#pragma unroll
  for (int j = 0; j < 4; ++j)
    tile[ty + j * 8][tx] = W[(size_t)(k0 + ty + j * 8) * 1024 + n0 + tx];
  __syncthreads();
#pragma unroll
  for (int j = 0; j < 4; ++j)
    out[(size_t)(n0 + ty + j * 8) * 1024 + k0 + tx] = f2bf(tile[tx][ty + j * 8]);
}

// ---------------- GEMM core 128x128 (m97 shape), BK=64, XOR-swizzled LDS ----------------
// Single Sh array (As|Bs views) so the epilogue can reuse all 32 KB for transposes.
#define GEMM_PROLOGUE128()                                                     \
  __shared__ __align__(16) unsigned short Sh[2 * 128 * 64];                    \
  unsigned short* const As = Sh;                                               \
  unsigned short* const Bs = Sh + 128 * 64;                                    \
  const int tid = threadIdx.x;                                                 \
  const int lane = tid & 63;                                                   \
  const int wid = tid >> 6;                                                    \
  const int col = lane & 15;                                                   \
  const int quad = lane >> 4;                                                  \
  const int m0 = blockIdx.x * 128;                                             \
  const int n0 = blockIdx.y * 128;                                             \
  const int wm = wid >> 1;                                                     \
  const int wn = wid & 1;                                                      \
  floatx4 acc[4][4];                                                           \
  _Pragma("unroll") for (int i = 0; i < 4; ++i)                                \
      _Pragma("unroll") for (int j = 0; j < 4; ++j)                            \
          acc[i][j] = (floatx4)(0.f);                                          \
  _Pragma("unroll 1") for (int kt = 0; kt < 16; ++kt) {                        \
    __syncthreads();                                                           \
    _Pragma("unroll") for (int call = 0; call < 4; ++call) {                   \
      int c = call * 256 + tid;                                                \
      int r = c >> 3, ch = c & 7;                                              \
      gload_lds16(A + (size_t)(m0 + r) * 1024 + kt * 64 + ((ch ^ (r & 7)) * 8),\
                  As + (size_t)(call * 256 + wid * 64) * 8);                   \
      gload_lds16(Bt + (size_t)(n0 + r) * 1024 + kt * 64 + ((ch ^ (r & 7)) * 8),\
                  Bs + (size_t)(call * 256 + wid * 64) * 8);                   \
    }                                                                          \
    __syncthreads();                                                           \
    _Pragma("unroll") for (int ks = 0; ks < 2; ++ks) {                         \
      short8 af[4], bf[4];                                                     \
      _Pragma("unroll") for (int rt = 0; rt < 4; ++rt) {                       \
        int row = wm * 64 + rt * 16 + col;                                     \
        af[rt] = *(const short8*)&As[row * 64 + (((ks * 4 + quad) ^ (row & 7)) * 8)]; \
      }                                                                        \
      _Pragma("unroll") for (int ct = 0; ct < 4; ++ct) {                       \
        int row = wn * 64 + ct * 16 + col;                                     \
        bf[ct] = *(const short8*)&Bs[row * 64 + (((ks * 4 + quad) ^ (row & 7)) * 8)]; \
      }                                                                        \
      _Pragma("unroll") for (int rt = 0; rt < 4; ++rt)                         \
          _Pragma("unroll") for (int ct = 0; ct < 4; ++ct)                     \
              acc[rt][ct] = MFMA16(af[rt], bf[ct], acc[rt][ct]);               \
    }                                                                          \
  }

// ---------------- GEMM core 64x128 (R0-proven), for gemm_out: 512 blocks = 2/CU ----------------
#define GEMM_PROLOGUE64()                                                      \
  __shared__ __align__(16) unsigned short As[64 * 64];                         \
  __shared__ __align__(16) unsigned short Bs[128 * 64];                        \
  const int tid = threadIdx.x;                                                 \
  const int lane = tid & 63;                                                   \
  const int wid = tid >> 6;                                                    \
  const int col = lane & 15;                                                   \
  const int quad = lane >> 4;                                                  \
  const int m0 = blockIdx.x * 64;                                              \
  const int n0 = blockIdx.y * 128;                                             \
  const int wm = wid >> 1;                                                     \
  const int wn = wid & 1;                                                      \
  floatx4 acc[2][4];                                                           \
  _Pragma("unroll") for (int i = 0; i < 2; ++i)                                \
      _Pragma("unroll") for (int j = 0; j < 4; ++j)                            \
          acc[i][j] = (floatx4)(0.f);                                          \
  _Pragma("unroll 1") for (int kt = 0; kt < 16; ++kt) {                        \
    __syncthreads();                                                           \
    _Pragma("unroll") for (int call = 0; call < 2; ++call) {                   \
      int c = call * 256 + tid;                                                \
      int r = c >> 3, ch = c & 7;                                              \
      gload_lds16(A + (size_t)(m0 + r) * 1024 + kt * 64 + ((ch ^ (r & 7)) * 8),\
                  As + (size_t)(call * 256 + wid * 64) * 8);                   \
    }                                                                          \
    _Pragma("unroll") for (int call = 0; call < 4; ++call) {                   \
      int c = call * 256 + tid;                                                \
      int r = c >> 3, ch = c & 7;                                              \
      gload_lds16(Bt + (size_t)(n0 + r) * 1024 + kt * 64 + ((ch ^ (r & 7)) * 8),\
                  Bs + (size_t)(call * 256 + wid * 64) * 8);                   \
    }                                                                          \
    __syncthreads();                                                           \
    _Pragma("unroll") for (int ks = 0; ks < 2; ++ks) {                         \
      short8 af[2], bf[4];                                                     \
      _Pragma("unroll") for (int rt = 0; rt < 2; ++rt) {                       \
        int row = wm * 32 + rt * 16 + col;                                     \
        af[rt] = *(const short8*)&As[row * 64 + (((ks * 4 + quad) ^ (row & 7)) * 8)]; \
      }                                                                        \
      _Pragma("unroll") for (int ct = 0; ct < 4; ++ct) {                       \
        int row = wn * 64 + ct * 16 + col;                                     \
        bf[ct] = *(const short8*)&Bs[row * 64 + (((ks * 4 + quad) ^ (row & 7)) * 8)]; \
      }                                                                        \
      _Pragma("unroll") for (int rt = 0; rt < 2; ++rt)                         \
          _Pragma("unroll") for (int ct = 0; ct < 4; ++ct)                     \
              acc[rt][ct] = MFMA16(af[rt], bf[ct], acc[rt][ct]);               \
    }                                                                          \
  }

__global__ __launch_bounds__(256, 3)
void gemm_qkv(const unsigned short* __restrict__ A, const unsigned short* __restrict__ Bt,
              const float* __restrict__ bq, const float* __restrict__ bk,
              const float* __restrict__ bv,
              unsigned short* __restrict__ Qo, unsigned short* __restrict__ Ko,
              unsigned short* __restrict__ Vo) {
  GEMM_PROLOGUE128()
  const int nseg = n0 >> 10;
  const float* bias = (nseg == 0) ? bq : ((nseg == 1) ? bk : bv);
  if (nseg == 2) {
    // V^T epilogue via LDS transpose: K-loop staging LDS is dead -> write the whole
    // 128x128 V block transposed (8B stores, XOR-swizzled mb^(cl&31), bijective),
    // then stream out fully-coalesced 16B rows. Replaces 8B-per-4KB-stride scatter.
    __syncthreads();  // all waves' fragment ds_reads done before Sh overwrite
    const int cb = n0 & 1023;
#pragma unroll
    for (int rt = 0; rt < 4; ++rt) {
#pragma unroll
      for (int ct = 0; ct < 4; ++ct) {
        int cl = wn * 64 + ct * 16 + col;     // V-col local 0..127
        int mb = wm * 16 + rt * 4 + quad;     // m 4-u16 chunk 0..31
        float bb = bias[cb + cl];
        uintx2 w;
        w[0] = pk2(acc[rt][ct][0] + bb, acc[rt][ct][1] + bb);
        w[1] = pk2(acc[rt][ct][2] + bb, acc[rt][ct][3] + bb);
        *(uintx2*)&Sh[cl * 128 + ((mb ^ (cl & 31)) * 4)] = w;
      }
    }
    __syncthreads();
    {
      int cl = tid >> 1, half = tid & 1;
      int hh = (cb >> 6) + (cl >> 6);
      int hd = cl & 63;
      int b_ = m0 >> 11;
      int s0 = (m0 & 2047) + half * 64;
      unsigned short* dst = Vo + (size_t)(b_ * 16 + hh) * 131072 + (size_t)hd * 2048 + s0;
#pragma unroll
      for (int k = 0; k < 8; ++k) {
        int mb0 = half * 16 + k * 2;
        uintx2 lo = *(const uintx2*)&Sh[cl * 128 + ((mb0 ^ (cl & 31)) * 4)];
        uintx2 hi = *(const uintx2*)&Sh[cl * 128 + (((mb0 + 1) ^ (cl & 31)) * 4)];
        uintx4 v;
        v[0] = lo[0]; v[1] = lo[1]; v[2] = hi[0]; v[3] = hi[1];
        *(uintx4*)&dst[k * 8] = v;
      }
    }
  } else {
    // Q/K epilogue via LDS transpose (same proven pattern as V): stage the whole
    // 128x128 tile as [256 rows = (cl>>6)*128 + ml][64 hd] with XOR-swizzled 16B
    // chunks (c16 ^ (row&7)); then each thread streams its own fully-contiguous
    // 128B output row (8 x 16B). Replaces 64 x 2B global scatter per thread.
    const float scl = (nseg == 0) ? (0.125f * LOG2E) : 1.0f;  // folds 1/8 and log2e
    __syncthreads();  // all waves' fragment ds_reads done before Sh overwrite
#pragma unroll
    for (int rt = 0; rt < 4; ++rt) {
#pragma unroll
      for (int ct = 0; ct < 4; ++ct) {
        int cl = wn * 64 + ct * 16 + col;          // tile-local col 0..127
        float bb = bias[(n0 & 1023) + cl];
        int c16 = (cl & 63) >> 3, wi = cl & 7;     // 16B chunk + within-chunk
#pragma unroll
        for (int i = 0; i < 4; ++i) {
          int ml = wm * 64 + rt * 16 + quad * 4 + i;
          int row = ((cl >> 6) << 7) + ml;         // 0..255
          Sh[row * 64 + ((c16 ^ (row & 7)) * 8) + wi] =
              f2bf((acc[rt][ct][i] + bb) * scl);
        }
      }
    }
    __syncthreads();
    {
      unsigned short* base = (nseg == 0) ? Qo : Ko;
      int clhi = tid >> 7, ml = tid & 127;
      int b_ = m0 >> 11, s = (m0 & 2047) + ml;
      int hh = ((n0 & 1023) >> 6) + clhi;
      unsigned short* dst = base + ((size_t)(b_ * 16 + hh) * 2048 + s) * 64;
#pragma unroll
      for (int c = 0; c < 8; ++c) {
        uintx4 v = *(const uintx4*)&Sh[tid * 64 + ((c ^ (tid & 7)) * 8)];
        *(uintx4*)&dst[c * 8] = v;
      }
    }
  }
}

__global__ __launch_bounds__(256, 5)
void gemm_out(const unsigned short* __restrict__ A, const unsigned short* __restrict__ Bt,
              const float* __restrict__ bo, float* __restrict__ Out) {
  GEMM_PROLOGUE64()
#pragma unroll
  for (int rt = 0; rt < 2; ++rt) {
#pragma unroll
    for (int ct = 0; ct < 4; ++ct) {
      int mg = m0 + wm * 32 + rt * 16 + quad * 4;
      int ng = n0 + wn * 64 + ct * 16 + col;
      float bb = bo[ng];
#pragma unroll
      for (int i = 0; i < 4; ++i)
        Out[(size_t)(mg + i) * 1024 + ng] = acc[rt][ct][i] + bb;
    }
  }
}

// ---------------- flash attention v20: best measured config (R11 44.8us; R13/R15 repro) ----
// 32 KB LDS, 4 blocks/CU, P-in-Ks, sum-via-MFMA, split vmcnt(4)/vmcnt(0) staging drain.
__global__ __launch_bounds__(256, 4)
void flash_attn(const unsigned short* __restrict__ Q, const unsigned short* __restrict__ K,
                const unsigned short* __restrict__ Vt, const float* __restrict__ mask,
                unsigned short* __restrict__ O) {
  __shared__ __align__(16) unsigned short Ks[128 * 64];   // K [kv][hd c8] chunk^(r&7); then P [q][c16]
  __shared__ __align__(16) unsigned short Vs[64 * 128];   // [hd][kv c16], chunk^(r&15)

  const int tid = threadIdx.x;
  const int lane = tid & 63;
  const int wid = tid >> 6;
  const int col = lane & 15;
  const int quad = lane >> 4;
  // balanced mapping: slot j-ranges {24..31, 0..7, 16..23, 8..15}
  const int slot = (int)(blockIdx.x >> 8);
  const int g = (int)(blockIdx.x & 255);
  const int h8 = g >> 5;
  const int bh = g & 31;
  const int j = (slot == 0) ? (31 - h8) : (slot == 1) ? h8 : (slot == 2) ? (23 - h8) : (8 + h8);
  const int b = bh >> 4, h = bh & 15;
  const int q0 = j * 64;
  const int tdiag = j >> 1;                   // diagonal kv-tile (128 wide)

  const unsigned short* Qp = Q + (size_t)bh * 2048 * 64;
  const unsigned short* Kp = K + (size_t)bh * 2048 * 64;
  const unsigned short* Vp = Vt + (size_t)bh * 64 * 2048;
  const float* mp = mask + b * 2048;

  const int lr8 = lane >> 3, lc8 = lane & 7;    // K/Q staging lane coords
  const int lr16 = lane >> 4, lc16 = lane & 15; // V staging lane coords
  const floatx4 fzero = (floatx4)(0.f);
  const floatx4 fone = (floatx4)(1.f);
  const short8 ones8 = (short8)(short)0x3F80;   // bf16 1.0 x8 (A-operand for row-sum MFMA)

  // stage Q rows [64][64] into Ks (swizzled): LDS[r][c] = Q[r][c ^ (r&7)]
#pragma unroll
  for (int i = 0; i < 2; ++i) {
    int seg = wid * 2 + i;
    int r = seg * 8 + lr8;
    gload_lds16(Qp + (size_t)(q0 + r) * 64 + ((lc8 ^ (r & 7)) * 8), Ks + seg * 512);
  }
  __syncthreads();  // staged Q visible
  short8 qf[2];
  {
    int q = wid * 16 + col;
#pragma unroll
    for (int ks = 0; ks < 2; ++ks)
      qf[ks] = *(const short8*)&Ks[q * 64 + (((ks * 4 + quad) ^ (q & 7)) * 8)];
  }
  // per-wave mask bitmask: bit t set iff kv-tile t contains any masked position
  unsigned int mbits = 0;
  for (int t = 0; t <= tdiag; ++t) {
    float2 mv = *(const float2*)&mp[t * 128 + lane * 2];
    unsigned long long bb = __ballot(mv.x != 1.f || mv.y != 1.f);
    mbits |= (bb ? 1u : 0u) << t;
  }

  floatx4 o[4];
#pragma unroll
  for (int dt = 0; dt < 4; ++dt) o[dt] = fzero;
  float mrow = -1e30f;
  float lrow = 0.f;

#pragma unroll 1
  for (int t = 0; t <= tdiag; ++t) {
    __syncthreads();  // prior iter's P/Vs reads (or prologue qf reads) done before restage
    // issue K then V staging (8 DMA ops/thread; vmcnt counts in issue order)
#pragma unroll
    for (int i = 0; i < 4; ++i) {  // K tile [128][64]
      int seg = wid * 4 + i;
      int r = seg * 8 + lr8;
      gload_lds16(Kp + (size_t)(t * 128 + r) * 64 + ((lc8 ^ (r & 7)) * 8), Ks + seg * 512);
    }
#pragma unroll
    for (int i = 0; i < 4; ++i) {  // V^T tile [64][128]
      int seg = wid * 4 + i;
      int r = seg * 4 + lr16;
      gload_lds16(Vp + (size_t)r * 2048 + t * 128 + ((lc16 ^ (r & 15)) * 8), Vs + seg * 512);
    }
    // wait K only (oldest 4 of 8): V stays in flight under QK + softmax
    asm volatile("s_waitcnt vmcnt(4)" ::: "memory");
    __builtin_amdgcn_sched_barrier(0);
    __builtin_amdgcn_s_barrier();  // all waves' K segments visible

    // S^T: [kv=128][q=16 per wave]  (scores already x log2e via Q scale)
    floatx4 sc[8];
    __builtin_amdgcn_s_setprio(1);
#pragma unroll
    for (int rt = 0; rt < 8; ++rt) {
      int kr = rt * 16 + col;
      short8 kf0 = *(const short8*)&Ks[kr * 64 + ((quad ^ (col & 7)) * 8)];
      short8 kf1 = *(const short8*)&Ks[kr * 64 + (((4 + quad) ^ (col & 7)) * 8)];
      floatx4 s0 = MFMA16(kf0, qf[0], fzero);
      sc[rt] = MFMA16(kf1, qf[1], s0);
    }
    __builtin_amdgcn_s_setprio(0);
    // Ks->P reuse barrier: LDS-only hazard; must NOT drain vmcnt (V still in flight)
    asm volatile("s_waitcnt lgkmcnt(0)" ::: "memory");
    __builtin_amdgcn_sched_barrier(0);
    __builtin_amdgcn_s_barrier();  // all waves' K-fragment reads done: Ks reusable as P

    // padding-mask additive bias only on tiles that actually have masked cols
    if (__builtin_amdgcn_readfirstlane(mbits >> t) & 1) {
#pragma unroll
      for (int rt = 0; rt < 8; ++rt) {
        floatx4 mm = *(const floatx4*)&mp[t * 128 + rt * 16 + quad * 4];
        sc[rt] += (fone - mm) * (-1.0e9f * LOG2E);
      }
    }
    if (t == tdiag) {  // causal diagonal: -1e9 * log2e (exp2 domain)
      int qg = q0 + wid * 16 + col;
#pragma unroll
      for (int rt = 0; rt < 8; ++rt)
#pragma unroll
        for (int i = 0; i < 4; ++i)
          if (t * 128 + rt * 16 + quad * 4 + i > qg) sc[rt][i] = -1.0e9f * LOG2E;
    }

    // online softmax, exp2 domain (per-lane q row stats; 2 shuffles per reduce)
    float mt = -1e30f;
#pragma unroll
    for (int rt = 0; rt < 8; ++rt)
      mt = fmaxf(mt, fmaxf(fmaxf(sc[rt][0], sc[rt][1]), fmaxf(sc[rt][2], sc[rt][3])));
    mt = fmaxf(mt, __shfl_xor(mt, 16));
    mt = fmaxf(mt, __shfl_xor(mt, 32));

    // defer-max (T13): keep old max when tile max grew by <= 8 => P bounded by 2^8
    const bool skip = (__all(mt - mrow <= 8.0f) != 0);  // wave-uniform
    float mn = mrow;
    if (!skip) {
      mn = fmaxf(mrow, mt);
      float alpha = EXP2(mrow - mn);
      mrow = mn;
      lrow *= alpha;
#pragma unroll
      for (int dt = 0; dt < 4; ++dt) o[dt] *= alpha;
    }
#pragma unroll
    for (int rt = 0; rt < 8; ++rt)
#pragma unroll
      for (int i = 0; i < 4; ++i) sc[rt][i] = EXP2(sc[rt][i] - mn);

    // write P rows (own wave) into Ks, swizzled: 8B at chunk (rt*2 + quad>>1) ^ col
    {
      int qloc = wid * 16 + col;
#pragma unroll
      for (int rt = 0; rt < 8; ++rt) {
        uintx2 w;
        w[0] = pk2(sc[rt][0], sc[rt][1]);
        w[1] = pk2(sc[rt][2], sc[rt][3]);
        int chunk = (rt * 2 + (quad >> 1)) ^ col;
        *(uintx2*)&Ks[qloc * 128 + chunk * 8 + (quad & 1) * 4] = w;
      }
    }
    // V ready gate: drain remaining DMA (V) and make all waves' segments visible
    asm volatile("s_waitcnt vmcnt(0)" ::: "memory");
    __builtin_amdgcn_sched_barrier(0);
    __builtin_amdgcn_s_barrier();

    // PV: O^T[d][q] += V^T * P^T; row-sum of P via ones-MFMA on the same fragments
    floatx4 ssum = fzero;
    __builtin_amdgcn_s_setprio(1);
#pragma unroll
    for (int ks = 0; ks < 4; ++ks) {
      int ch = ks * 4 + quad;
      short8 pf = *(const short8*)&Ks[(wid * 16 + col) * 128 + ((ch ^ col) * 8)];
      ssum = MFMA16(ones8, pf, ssum);   // D[i][q] = sum_kv P[kv][q] (same for all i)
#pragma unroll
      for (int dt = 0; dt < 4; ++dt) {
        short8 vf = *(const short8*)&Vs[(dt * 16 + col) * 128 + ((ch ^ col) * 8)];
        o[dt] = MFMA16(vf, pf, o[dt]);
      }
    }
    __builtin_amdgcn_s_setprio(0);
    lrow += ssum[0];
  }

  // epilogue: O^T regs: d = dt*16 + quad*4 + i, q = wid*16 + col
  {
    float inv = 1.0f / lrow;
    int qg = q0 + wid * 16 + col;
    unsigned short* dst = O + ((size_t)(b * 2048 + qg)) * 1024 + h * 64;
#pragma unroll
    for (int dt = 0; dt < 4; ++dt) {
      uintx2 pk;
      pk[0] = pk2(o[dt][0] * inv, o[dt][1] * inv);
      pk[1] = pk2(o[dt][2] * inv, o[dt][3] * inv);
      *(uintx2*)&dst[dt * 16 + quad * 4] = pk;
    }
  }
}

// ---------------- launch ----------------
extern "C" void kernel_launch(void* const* d_in, const int* in_sizes, int n_in,
                              void* d_out, int out_size, void* d_ws, size_t ws_size,
                              hipStream_t stream) {
  (void)in_sizes; (void)n_in; (void)out_size; (void)ws_size;
  const float* x  = (const float*)d_in[0];
  const float* mask = (const float*)d_in[1];
  const float* Wq = (const float*)d_in[2];
  const float* bq = (const float*)d_in[3];
  const float* Wk = (const float*)d_in[4];
  const float* bk = (const float*)d_in[5];
  const float* Wv = (const float*)d_in[6];
  const float* bv = (const float*)d_in[7];
  const float* Wo = (const float*)d_in[8];
  const float* bo = (const float*)d_in[9];
  float* out = (float*)d_out;

  char* ws = (char*)d_ws;
  unsigned short* xb    = (unsigned short*)(ws);                    // 8 MB
  unsigned short* Wqkvt = (unsigned short*)(ws + (8u << 20));       // 6 MB
  unsigned short* Wot   = (unsigned short*)(ws + (14u << 20));      // 2 MB
  unsigned short* Qb    = (unsigned short*)(ws + (16u << 20));      // 8 MB
  unsigned short* Kb    = (unsigned short*)(ws + (24u << 20));      // 8 MB
  unsigned short* Vtb   = (unsigned short*)(ws + (32u << 20));      // 8 MB
  unsigned short* Ao    = (unsigned short*)(ws + (40u << 20));      // 8 MB (48 MB total)

  convert_x<<<4096, 256, 0, stream>>>(x, xb);
  transpose_w<<<dim3(32, 32, 4), dim3(32, 8), 0, stream>>>(Wq, Wk, Wv, Wo, Wqkvt, Wot);
  gemm_qkv<<<dim3(32, 24), 256, 0, stream>>>(xb, Wqkvt, bq, bk, bv, Qb, Kb, Vtb);
  flash_attn<<<dim3(1024), 256, 0, stream>>>(Qb, Kb, Vtb, mask, Ao);
  gemm_out<<<dim3(64, 8), 256, 0, stream>>>(Ao, Wot, bo, out);
}

// Round 17
// 180.016 us; speedup vs baseline: 1.0434x; 1.0434x over previous
//
#include <hip/hip_runtime.h>
#include <hip/hip_bf16.h>
#include <cstdint>
#include <cstddef>

// ---- types ----
typedef __attribute__((ext_vector_type(8))) short short8;       // 8 bf16 (4 VGPR) MFMA frag
typedef __attribute__((ext_vector_type(4))) float floatx4;      // MFMA accumulator
typedef __attribute__((ext_vector_type(2))) unsigned int uintx2;     // 8B vector st
typedef __attribute__((ext_vector_type(4))) unsigned int uintx4;     // 16B vector st

#define MFMA16(a, b, c) __builtin_amdgcn_mfma_f32_16x16x32_bf16((a), (b), (c), 0, 0, 0)
#define LOG2E 1.44269504088896340736f
#define EXP2(x) __builtin_amdgcn_exp2f(x)

__device__ __forceinline__ unsigned short f2bf(float f) {
  unsigned int u = __builtin_bit_cast(unsigned int, f);
  u += 0x7fffu + ((u >> 16) & 1u);          // RNE
  return (unsigned short)(u >> 16);
}

// packed bf16 pair via v_cvt_pk_bf16_f32 (RNE); memcpy avoids bit_cast restriction
__device__ __forceinline__ unsigned int pk2(float a, float b) {
  float2 f; f.x = a; f.y = b;
  __hip_bfloat162 h = __float22bfloat162_rn(f);
  unsigned int u;
  __builtin_memcpy(&u, &h, 4);
  return u;
}

typedef __attribute__((address_space(1))) void gvoid_t;
typedef __attribute__((address_space(3))) void svoid_t;
__device__ __forceinline__ void gload_lds16(const void* g, void* l) {
  // LDS dest = wave-uniform base + lane*16; global side is per-lane addresses.
  __builtin_amdgcn_global_load_lds((gvoid_t*)(uintptr_t)g, (svoid_t*)(uintptr_t)l, 16, 0, 0);
}

// ---------------- convert x: fp32 -> bf16 ----------------
__global__ void convert_x(const float* __restrict__ x, unsigned short* __restrict__ xb) {
  int i = (blockIdx.x * 256 + threadIdx.x) * 4;
  floatx4 v = *(const floatx4*)(x + i);
  uintx2 o;
  o[0] = pk2(v[0], v[1]);
  o[1] = pk2(v[2], v[3]);
  *(uintx2*)(xb + i) = o;
}

// ---------------- transpose weights -> bf16 N x K ----------------
__global__ void transpose_w(const float* __restrict__ Wq, const float* __restrict__ Wk,
                            const float* __restrict__ Wv, const float* __restrict__ Wo,
                            unsigned short* __restrict__ Wqkvt, unsigned short* __restrict__ Wot) {
  __shared__ float tile[32][33];
  int z = blockIdx.z;
  const float* W = (z == 0) ? Wq : (z == 1) ? Wk : (z == 2) ? Wv : Wo;
  unsigned short* out = (z == 3) ? Wot : (Wqkvt + (size_t)z * 1024 * 1024);
  int n0 = blockIdx.x * 32, k0 = blockIdx.y * 32;
  int tx = threadIdx.x, ty = threadIdx.y;            // block (32,8)
#pragma unroll
  for (int j = 0; j < 4; ++j)
    tile[ty + j * 8][tx] = W[(size_t)(k0 + ty + j * 8) * 1024 + n0 + tx];
  __syncthreads();
#pragma unroll
  for (int j = 0; j < 4; ++j)
    out[(size_t)(n0 + ty + j * 8) * 1024 + k0 + tx] = f2bf(tile[tx][ty + j * 8]);
}

// ---------------- GEMM core 128x128 (m97 shape), BK=64, XOR-swizzled LDS ----------------
// Single Sh array (As|Bs views) so the epilogue can reuse all 32 KB for V^T transpose.
#define GEMM_PROLOGUE128()                                                     \
  __shared__ __align__(16) unsigned short Sh[2 * 128 * 64];                    \
  unsigned short* const As = Sh;                                               \
  unsigned short* const Bs = Sh + 128 * 64;                                    \
  const int tid = threadIdx.x;                                                 \
  const int lane = tid & 63;                                                   \
  const int wid = tid >> 6;                                                    \
  const int col = lane & 15;                                                   \
  const int quad = lane >> 4;                                                  \
  const int m0 = blockIdx.x * 128;                                             \
  const int n0 = blockIdx.y * 128;                                             \
  const int wm = wid >> 1;                                                     \
  const int wn = wid & 1;                                                      \
  floatx4 acc[4][4];                                                           \
  _Pragma("unroll") for (int i = 0; i < 4; ++i)                                \
      _Pragma("unroll") for (int j = 0; j < 4; ++j)                            \
          acc[i][j] = (floatx4)(0.f);                                          \
  _Pragma("unroll 1") for (int kt = 0; kt < 16; ++kt) {                        \
    __syncthreads();                                                           \
    _Pragma("unroll") for (int call = 0; call < 4; ++call) {                   \
      int c = call * 256 + tid;                                                \
      int r = c >> 3, ch = c & 7;                                              \
      gload_lds16(A + (size_t)(m0 + r) * 1024 + kt * 64 + ((ch ^ (r & 7)) * 8),\
                  As + (size_t)(call * 256 + wid * 64) * 8);                   \
      gload_lds16(Bt + (size_t)(n0 + r) * 1024 + kt * 64 + ((ch ^ (r & 7)) * 8),\
                  Bs + (size_t)(call * 256 + wid * 64) * 8);                   \
    }                                                                          \
    __syncthreads();                                                           \
    _Pragma("unroll") for (int ks = 0; ks < 2; ++ks) {                         \
      short8 af[4], bf[4];                                                     \
      _Pragma("unroll") for (int rt = 0; rt < 4; ++rt) {                       \
        int row = wm * 64 + rt * 16 + col;                                     \
        af[rt] = *(const short8*)&As[row * 64 + (((ks * 4 + quad) ^ (row & 7)) * 8)]; \
      }                                                                        \
      _Pragma("unroll") for (int ct = 0; ct < 4; ++ct) {                       \
        int row = wn * 64 + ct * 16 + col;                                     \
        bf[ct] = *(const short8*)&Bs[row * 64 + (((ks * 4 + quad) ^ (row & 7)) * 8)]; \
      }                                                                        \
      _Pragma("unroll") for (int rt = 0; rt < 4; ++rt)                         \
          _Pragma("unroll") for (int ct = 0; ct < 4; ++ct)                     \
              acc[rt][ct] = MFMA16(af[rt], bf[ct], acc[rt][ct]);               \
    }                                                                          \
  }

// ---------------- GEMM core 64x128 (R0-proven), for gemm_out: 512 blocks = 2/CU ----------------
#define GEMM_PROLOGUE64()                                                      \
  __shared__ __align__(16) unsigned short As[64 * 64];                         \
  __shared__ __align__(16) unsigned short Bs[128 * 64];                        \
  const int tid = threadIdx.x;                                                 \
  const int lane = tid & 63;                                                   \
  const int wid = tid >> 6;                                                    \
  const int col = lane & 15;                                                   \
  const int quad = lane >> 4;                                                  \
  const int m0 = blockIdx.x * 64;                                              \
  const int n0 = blockIdx.y * 128;                                             \
  const int wm = wid >> 1;                                                     \
  const int wn = wid & 1;                                                      \
  floatx4 acc[2][4];                                                           \
  _Pragma("unroll") for (int i = 0; i < 2; ++i)                                \
      _Pragma("unroll") for (int j = 0; j < 4; ++j)                            \
          acc[i][j] = (floatx4)(0.f);                                          \
  _Pragma("unroll 1") for (int kt = 0; kt < 16; ++kt) {                        \
    __syncthreads();                                                           \
    _Pragma("unroll") for (int call = 0; call < 2; ++call) {                   \
      int c = call * 256 + tid;                                                \
      int r = c >> 3, ch = c & 7;                                              \
      gload_lds16(A + (size_t)(m0 + r) * 1024 + kt * 64 + ((ch ^ (r & 7)) * 8),\
                  As + (size_t)(call * 256 + wid * 64) * 8);                   \
    }                                                                          \
    _Pragma("unroll") for (int call = 0; call < 4; ++call) {                   \
      int c = call * 256 + tid;                                                \
      int r = c >> 3, ch = c & 7;                                              \
      gload_lds16(Bt + (size_t)(n0 + r) * 1024 + kt * 64 + ((ch ^ (r & 7)) * 8),\
                  Bs + (size_t)(call * 256 + wid * 64) * 8);                   \
    }                                                                          \
    __syncthreads();                                                           \
    _Pragma("unroll") for (int ks = 0; ks < 2; ++ks) {                         \
      short8 af[2], bf[4];                                                     \
      _Pragma("unroll") for (int rt = 0; rt < 2; ++rt) {                       \
        int row = wm * 32 + rt * 16 + col;                                     \
        af[rt] = *(const short8*)&As[row * 64 + (((ks * 4 + quad) ^ (row & 7)) * 8)]; \
      }                                                                        \
      _Pragma("unroll") for (int ct = 0; ct < 4; ++ct) {                       \
        int row = wn * 64 + ct * 16 + col;                                     \
        bf[ct] = *(const short8*)&Bs[row * 64 + (((ks * 4 + quad) ^ (row & 7)) * 8)]; \
      }                                                                        \
      _Pragma("unroll") for (int rt = 0; rt < 2; ++rt)                         \
          _Pragma("unroll") for (int ct = 0; ct < 4; ++ct)                     \
              acc[rt][ct] = MFMA16(af[rt], bf[ct], acc[rt][ct]);               \
    }                                                                          \
  }

__global__ __launch_bounds__(256, 3)
void gemm_qkv(const unsigned short* __restrict__ A, const unsigned short* __restrict__ Bt,
              const float* __restrict__ bq, const float* __restrict__ bk,
              const float* __restrict__ bv,
              unsigned short* __restrict__ Qo, unsigned short* __restrict__ Ko,
              unsigned short* __restrict__ Vo) {
  GEMM_PROLOGUE128()
  const int nseg = n0 >> 10;
  const float* bias = (nseg == 0) ? bq : ((nseg == 1) ? bk : bv);
  if (nseg == 2) {
    // V^T epilogue via LDS transpose: K-loop staging LDS is dead -> write the whole
    // 128x128 V block transposed (8B stores, XOR-swizzled mb^(cl&31), bijective),
    // then stream out fully-coalesced 16B rows. Replaces 8B-per-4KB-stride scatter.
    __syncthreads();  // all waves' fragment ds_reads done before Sh overwrite
    const int cb = n0 & 1023;
#pragma unroll
    for (int rt = 0; rt < 4; ++rt) {
#pragma unroll
      for (int ct = 0; ct < 4; ++ct) {
        int cl = wn * 64 + ct * 16 + col;     // V-col local 0..127
        int mb = wm * 16 + rt * 4 + quad;     // m 4-u16 chunk 0..31
        float bb = bias[cb + cl];
        uintx2 w;
        w[0] = pk2(acc[rt][ct][0] + bb, acc[rt][ct][1] + bb);
        w[1] = pk2(acc[rt][ct][2] + bb, acc[rt][ct][3] + bb);
        *(uintx2*)&Sh[cl * 128 + ((mb ^ (cl & 31)) * 4)] = w;
      }
    }
    __syncthreads();
    {
      int cl = tid >> 1, half = tid & 1;
      int hh = (cb >> 6) + (cl >> 6);
      int hd = cl & 63;
      int b_ = m0 >> 11;
      int s0 = (m0 & 2047) + half * 64;
      unsigned short* dst = Vo + (size_t)(b_ * 16 + hh) * 131072 + (size_t)hd * 2048 + s0;
#pragma unroll
      for (int k = 0; k < 8; ++k) {
        int mb0 = half * 16 + k * 2;
        uintx2 lo = *(const uintx2*)&Sh[cl * 128 + ((mb0 ^ (cl & 31)) * 4)];
        uintx2 hi = *(const uintx2*)&Sh[cl * 128 + (((mb0 + 1) ^ (cl & 31)) * 4)];
        uintx4 v;
        v[0] = lo[0]; v[1] = lo[1]; v[2] = hi[0]; v[3] = hi[1];
        *(uintx4*)&dst[k * 8] = v;
      }
    }
  } else {
#pragma unroll
    for (int rt = 0; rt < 4; ++rt) {
#pragma unroll
      for (int ct = 0; ct < 4; ++ct) {
        int mg = m0 + wm * 64 + rt * 16 + quad * 4;
        int ng = n0 + wn * 64 + ct * 16 + col;
        int c = ng & 1023;
        int hh = c >> 6, hd = c & 63;
        int b_ = mg >> 11, s = mg & 2047;
        float bb = bias[c];
        unsigned short* dst =
            ((nseg == 0) ? Qo : Ko) + ((size_t)(b_ * 16 + hh) * 2048 + s) * 64 + hd;
        // Q scale folds 1/sqrt(64) AND log2(e) (exp2-domain softmax downstream)
        float scl = (nseg == 0) ? (0.125f * LOG2E) : 1.0f;
#pragma unroll
        for (int i = 0; i < 4; ++i) dst[(size_t)i * 64] = f2bf((acc[rt][ct][i] + bb) * scl);
      }
    }
  }
}

__global__ __launch_bounds__(256, 5)
void gemm_out(const unsigned short* __restrict__ A, const unsigned short* __restrict__ Bt,
              const float* __restrict__ bo, float* __restrict__ Out) {
  GEMM_PROLOGUE64()
#pragma unroll
  for (int rt = 0; rt < 2; ++rt) {
#pragma unroll
    for (int ct = 0; ct < 4; ++ct) {
      int mg = m0 + wm * 32 + rt * 16 + quad * 4;
      int ng = n0 + wn * 64 + ct * 16 + col;
      float bb = bo[ng];
#pragma unroll
      for (int i = 0; i < 4; ++i)
        Out[(size_t)(mg + i) * 1024 + ng] = acc[rt][ct][i] + bb;
    }
  }
}

// ---------------- flash attention v20: best measured config (R11 44.8us; R13/R15 repro) ----
// 32 KB LDS, 4 blocks/CU, P-in-Ks, sum-via-MFMA, split vmcnt(4)/vmcnt(0) staging drain.
__global__ __launch_bounds__(256, 4)
void flash_attn(const unsigned short* __restrict__ Q, const unsigned short* __restrict__ K,
                const unsigned short* __restrict__ Vt, const float* __restrict__ mask,
                unsigned short* __restrict__ O) {
  __shared__ __align__(16) unsigned short Ks[128 * 64];   // K [kv][hd c8] chunk^(r&7); then P [q][c16]
  __shared__ __align__(16) unsigned short Vs[64 * 128];   // [hd][kv c16], chunk^(r&15)

  const int tid = threadIdx.x;
  const int lane = tid & 63;
  const int wid = tid >> 6;
  const int col = lane & 15;
  const int quad = lane >> 4;
  // balanced mapping: slot j-ranges {24..31, 0..7, 16..23, 8..15}
  const int slot = (int)(blockIdx.x >> 8);
  const int g = (int)(blockIdx.x & 255);
  const int h8 = g >> 5;
  const int bh = g & 31;
  const int j = (slot == 0) ? (31 - h8) : (slot == 1) ? h8 : (slot == 2) ? (23 - h8) : (8 + h8);
  const int b = bh >> 4, h = bh & 15;
  const int q0 = j * 64;
  const int tdiag = j >> 1;                   // diagonal kv-tile (128 wide)

  const unsigned short* Qp = Q + (size_t)bh * 2048 * 64;
  const unsigned short* Kp = K + (size_t)bh * 2048 * 64;
  const unsigned short* Vp = Vt + (size_t)bh * 64 * 2048;
  const float* mp = mask + b * 2048;

  const int lr8 = lane >> 3, lc8 = lane & 7;    // K/Q staging lane coords
  const int lr16 = lane >> 4, lc16 = lane & 15; // V staging lane coords
  const floatx4 fzero = (floatx4)(0.f);
  const floatx4 fone = (floatx4)(1.f);
  const short8 ones8 = (short8)(short)0x3F80;   // bf16 1.0 x8 (A-operand for row-sum MFMA)

  // stage Q rows [64][64] into Ks (swizzled): LDS[r][c] = Q[r][c ^ (r&7)]
#pragma unroll
  for (int i = 0; i < 2; ++i) {
    int seg = wid * 2 + i;
    int r = seg * 8 + lr8;
    gload_lds16(Qp + (size_t)(q0 + r) * 64 + ((lc8 ^ (r & 7)) * 8), Ks + seg * 512);
  }
  __syncthreads();  // staged Q visible
  short8 qf[2];
  {
    int q = wid * 16 + col;
#pragma unroll
    for (int ks = 0; ks < 2; ++ks)
      qf[ks] = *(const short8*)&Ks[q * 64 + (((ks * 4 + quad) ^ (q & 7)) * 8)];
  }
  // per-wave mask bitmask: bit t set iff kv-tile t contains any masked position
  unsigned int mbits = 0;
  for (int t = 0; t <= tdiag; ++t) {
    float2 mv = *(const float2*)&mp[t * 128 + lane * 2];
    unsigned long long bb = __ballot(mv.x != 1.f || mv.y != 1.f);
    mbits |= (bb ? 1u : 0u) << t;
  }

  floatx4 o[4];
#pragma unroll
  for (int dt = 0; dt < 4; ++dt) o[dt] = fzero;
  float mrow = -1e30f;
  float lrow = 0.f;

#pragma unroll 1
  for (int t = 0; t <= tdiag; ++t) {
    __syncthreads();  // prior iter's P/Vs reads (or prologue qf reads) done before restage
    // issue K then V staging (8 DMA ops/thread; vmcnt counts in issue order)
#pragma unroll
    for (int i = 0; i < 4; ++i) {  // K tile [128][64]
      int seg = wid * 4 + i;
      int r = seg * 8 + lr8;
      gload_lds16(Kp + (size_t)(t * 128 + r) * 64 + ((lc8 ^ (r & 7)) * 8), Ks + seg * 512);
    }
#pragma unroll
    for (int i = 0; i < 4; ++i) {  // V^T tile [64][128]
      int seg = wid * 4 + i;
      int r = seg * 4 + lr16;
      gload_lds16(Vp + (size_t)r * 2048 + t * 128 + ((lc16 ^ (r & 15)) * 8), Vs + seg * 512);
    }
    // wait K only (oldest 4 of 8): V stays in flight under QK + softmax
    asm volatile("s_waitcnt vmcnt(4)" ::: "memory");
    __builtin_amdgcn_sched_barrier(0);
    __builtin_amdgcn_s_barrier();  // all waves' K segments visible

    // S^T: [kv=128][q=16 per wave]  (scores already x log2e via Q scale)
    floatx4 sc[8];
    __builtin_amdgcn_s_setprio(1);
#pragma unroll
    for (int rt = 0; rt < 8; ++rt) {
      int kr = rt * 16 + col;
      short8 kf0 = *(const short8*)&Ks[kr * 64 + ((quad ^ (col & 7)) * 8)];
      short8 kf1 = *(const short8*)&Ks[kr * 64 + (((4 + quad) ^ (col & 7)) * 8)];
      floatx4 s0 = MFMA16(kf0, qf[0], fzero);
      sc[rt] = MFMA16(kf1, qf[1], s0);
    }
    __builtin_amdgcn_s_setprio(0);
    // Ks->P reuse barrier: LDS-only hazard; must NOT drain vmcnt (V still in flight)
    asm volatile("s_waitcnt lgkmcnt(0)" ::: "memory");
    __builtin_amdgcn_sched_barrier(0);
    __builtin_amdgcn_s_barrier();  // all waves' K-fragment reads done: Ks reusable as P

    // padding-mask additive bias only on tiles that actually have masked cols
    if (__builtin_amdgcn_readfirstlane(mbits >> t) & 1) {
#pragma unroll
      for (int rt = 0; rt < 8; ++rt) {
        floatx4 mm = *(const floatx4*)&mp[t * 128 + rt * 16 + quad * 4];
        sc[rt] += (fone - mm) * (-1.0e9f * LOG2E);
      }
    }
    if (t == tdiag) {  // causal diagonal: -1e9 * log2e (exp2 domain)
      int qg = q0 + wid * 16 + col;
#pragma unroll
      for (int rt = 0; rt < 8; ++rt)
#pragma unroll
        for (int i = 0; i < 4; ++i)
          if (t * 128 + rt * 16 + quad * 4 + i > qg) sc[rt][i] = -1.0e9f * LOG2E;
    }

    // online softmax, exp2 domain (per-lane q row stats; 2 shuffles per reduce)
    float mt = -1e30f;
#pragma unroll
    for (int rt = 0; rt < 8; ++rt)
      mt = fmaxf(mt, fmaxf(fmaxf(sc[rt][0], sc[rt][1]), fmaxf(sc[rt][2], sc[rt][3])));
    mt = fmaxf(mt, __shfl_xor(mt, 16));
    mt = fmaxf(mt, __shfl_xor(mt, 32));

    // defer-max (T13): keep old max when tile max grew by <= 8 => P bounded by 2^8
    const bool skip = (__all(mt - mrow <= 8.0f) != 0);  // wave-uniform
    float mn = mrow;
    if (!skip) {
      mn = fmaxf(mrow, mt);
      float alpha = EXP2(mrow - mn);
      mrow = mn;
      lrow *= alpha;
#pragma unroll
      for (int dt = 0; dt < 4; ++dt) o[dt] *= alpha;
    }
#pragma unroll
    for (int rt = 0; rt < 8; ++rt)
#pragma unroll
      for (int i = 0; i < 4; ++i) sc[rt][i] = EXP2(sc[rt][i] - mn);

    // write P rows (own wave) into Ks, swizzled: 8B at chunk (rt*2 + quad>>1) ^ col
    {
      int qloc = wid * 16 + col;
#pragma unroll
      for (int rt = 0; rt < 8; ++rt) {
        uintx2 w;
        w[0] = pk2(sc[rt][0], sc[rt][1]);
        w[1] = pk2(sc[rt][2], sc[rt][3]);
        int chunk = (rt * 2 + (quad >> 1)) ^ col;
        *(uintx2*)&Ks[qloc * 128 + chunk * 8 + (quad & 1) * 4] = w;
      }
    }
    // V ready gate: drain remaining DMA (V) and make all waves' segments visible
    asm volatile("s_waitcnt vmcnt(0)" ::: "memory");
    __builtin_amdgcn_sched_barrier(0);
    __builtin_amdgcn_s_barrier();

    // PV: O^T[d][q] += V^T * P^T; row-sum of P via ones-MFMA on the same fragments
    floatx4 ssum = fzero;
    __builtin_amdgcn_s_setprio(1);
#pragma unroll
    for (int ks = 0; ks < 4; ++ks) {
      int ch = ks * 4 + quad;
      short8 pf = *(const short8*)&Ks[(wid * 16 + col) * 128 + ((ch ^ col) * 8)];
      ssum = MFMA16(ones8, pf, ssum);   // D[i][q] = sum_kv P[kv][q] (same for all i)
#pragma unroll
      for (int dt = 0; dt < 4; ++dt) {
        short8 vf = *(const short8*)&Vs[(dt * 16 + col) * 128 + ((ch ^ col) * 8)];
        o[dt] = MFMA16(vf, pf, o[dt]);
      }
    }
    __builtin_amdgcn_s_setprio(0);
    lrow += ssum[0];
  }

  // epilogue: O^T regs: d = dt*16 + quad*4 + i, q = wid*16 + col
  {
    float inv = 1.0f / lrow;
    int qg = q0 + wid * 16 + col;
    unsigned short* dst = O + ((size_t)(b * 2048 + qg)) * 1024 + h * 64;
#pragma unroll
    for (int dt = 0; dt < 4; ++dt) {
      uintx2 pk;
      pk[0] = pk2(o[dt][0] * inv, o[dt][1] * inv);
      pk[1] = pk2(o[dt][2] * inv, o[dt][3] * inv);
      *(uintx2*)&dst[dt * 16 + quad * 4] = pk;
    }
  }
}

// ---------------- launch ----------------
extern "C" void kernel_launch(void* const* d_in, const int* in_sizes, int n_in,
                              void* d_out, int out_size, void* d_ws, size_t ws_size,
                              hipStream_t stream) {
  (void)in_sizes; (void)n_in; (void)out_size; (void)ws_size;
  const float* x  = (const float*)d_in[0];
  const float* mask = (const float*)d_in[1];
  const float* Wq = (const float*)d_in[2];
  const float* bq = (const float*)d_in[3];
  const float* Wk = (const float*)d_in[4];
  const float* bk = (const float*)d_in[5];
  const float* Wv = (const float*)d_in[6];
  const float* bv = (const float*)d_in[7];
  const float* Wo = (const float*)d_in[8];
  const float* bo = (const float*)d_in[9];
  float* out = (float*)d_out;

  char* ws = (char*)d_ws;
  unsigned short* xb    = (unsigned short*)(ws);                    // 8 MB
  unsigned short* Wqkvt = (unsigned short*)(ws + (8u << 20));       // 6 MB
  unsigned short* Wot   = (unsigned short*)(ws + (14u << 20));      // 2 MB
  unsigned short* Qb    = (unsigned short*)(ws + (16u << 20));      // 8 MB
  unsigned short* Kb    = (unsigned short*)(ws + (24u << 20));      // 8 MB
  unsigned short* Vtb   = (unsigned short*)(ws + (32u << 20));      // 8 MB
  unsigned short* Ao    = (unsigned short*)(ws + (40u << 20));      // 8 MB (48 MB total)

  convert_x<<<4096, 256, 0, stream>>>(x, xb);
  transpose_w<<<dim3(32, 32, 4), dim3(32, 8), 0, stream>>>(Wq, Wk, Wv, Wo, Wqkvt, Wot);
  gemm_qkv<<<dim3(32, 24), 256, 0, stream>>>(xb, Wqkvt, bq, bk, bv, Qb, Kb, Vtb);
  flash_attn<<<dim3(1024), 256, 0, stream>>>(Qb, Kb, Vtb, mask, Ao);
  gemm_out<<<dim3(64, 8), 256, 0, stream>>>(Ao, Wot, bo, out);
}